// Round 12
// baseline (94.472 us; speedup 1.0000x reference)
//
#include <hip/hip_runtime.h>
#include <stdint.h>

// Y = tanh(X @ W + b):  M=65536 (8*64*128), K=512, N=512, all fp32.
// R12: LDS-traffic-minimal, BARRIER-FREE design.
//   Diagnosis (R7-R11): MfmaUtil pinned at 13% because the per-CU LDS pipe
//   was ~90% busy (144 b128-class ops x 12cy per step-period). Fix the pipe,
//   not the schedule.
//   - Wave tile 32x128: A-frags/k16 = 1 -> 4 MFMA per A-read (was 2).
//   - B NEVER in LDS: cvtW emits W in MFMA-fragment order
//     [bn][nf][step][kk][lane]x16B, so B loads are perfectly coalesced 1KB
//     dwordx4 from the L2-hot 512KB image straight to registers.
//     (R10 failed on uncoalesced fragment gathers; this fixes that.)
//   - A LDS is WAVE-PRIVATE (wave writes & reads only its own 32 rows):
//     ZERO barriers. Each wave = independent counted-vmcnt pipeline with
//     invariant queue [B(t):8, A(t+1):4]; vmcnt(12)/vmcnt(8), 0 only at tail.
//   LDS ops: 4 b128/wave/step (was 12). ~100 VGPR + 64 AGPR -> 2 waves/SIMD
//   ((256,2), cap 256, no spill); occupancy low but waves never co-wait.

typedef short bf16x8 __attribute__((ext_vector_type(8)));
typedef float f32x16 __attribute__((ext_vector_type(16)));

#define KTOT 512
#define NTOT 512
#define WT_BYTES   524288ull      // 512*512*2
#define WS_NEEDED  WT_BYTES

__device__ __forceinline__ uint32_t pk2(float a, float b) {
  uint16_t lo = __builtin_bit_cast(uint16_t, (__bf16)a);   // RNE
  uint16_t hi = __builtin_bit_cast(uint16_t, (__bf16)b);
  return (uint32_t)lo | ((uint32_t)hi << 16);
}

__device__ __forceinline__ float fast_tanh(float z) {
  float t = __builtin_amdgcn_exp2f(z * 2.8853900817779268f);
  return 1.0f - 2.0f * __builtin_amdgcn_rcpf(t + 1.0f);
}

// ---- pass 1: W fp32 [k][n] -> bf16 fragment-order image ----
// chunk c (0..32767): lane=c&63, kk=(c>>6)&1, step=(c>>7)&15, nf=(c>>11)&3,
// bq=c>>13. 16B = 8 bf16 of column (bq*128+nf*32+(lane&31)),
// k = step*32 + kk*16 + (lane>>5)*8 + [0..7]. Stored flat at Wt + c*16.
__global__ __launch_bounds__(256)
void cvtW_kernel(const float* __restrict__ W, uint8_t* __restrict__ Wt) {
  const int c    = blockIdx.x * 256 + threadIdx.x;   // 0..32767
  const int lane = c & 63;
  const int kk   = (c >> 6) & 1;
  const int st   = (c >> 7) & 15;
  const int nf   = (c >> 11) & 3;
  const int bq   = c >> 13;
  const int col  = bq * 128 + nf * 32 + (lane & 31);
  const int kb   = st * 32 + kk * 16 + (lane >> 5) * 8;
  float e[8];
#pragma unroll
  for (int i = 0; i < 8; ++i) e[i] = W[(size_t)(kb + i) * NTOT + col];
  *(uint4*)(Wt + (size_t)c * 16) =
      make_uint4(pk2(e[0], e[1]), pk2(e[2], e[3]),
                 pk2(e[4], e[5]), pk2(e[6], e[7]));
}

// ---------------- pass 2: barrier-free GEMM + bias + tanh ----------------
__global__ __launch_bounds__(256, 2)
void hotdd_fused(const float* __restrict__ X, const uint8_t* __restrict__ Wt,
                 const float* __restrict__ Bv, float* __restrict__ Y) {
  __shared__ uint8_t Ab[2][8192];   // per buf: 4 waves x [32 rows][64B], private

  // XCD swizzle: the 4 bn-blocks sharing an X strip -> same XCD, adjacent.
  const int d  = blockIdx.x;
  const int bm = ((d >> 5) << 3) | (d & 7);   // 0..511
  const int bn = (d >> 3) & 3;                // 0..3

  const int tid  = threadIdx.x;
  const int lane = tid & 63;
  const int wv   = tid >> 6;
  const int lo5  = lane & 31;
  const int hi1  = lane >> 5;

  // ---- A staging (wave-private strip = rows bm*128 + wv*32 + [0..31]):
  // write: lane -> row lane>>1, k-half lane&1 (16 fp32 -> 2x16B bf16)
  // read : lane -> row lane&31, chunk kk*2+hi1 (16B)
  const int arow  = lane >> 1;
  const int ahalf = lane & 1;
  const float* pA = X + (size_t)(bm * 128 + wv * 32 + arow) * KTOT + ahalf * 16;
  const int awr = wv * 2048 + arow * 64 + ahalf * 32;
  const int ard = wv * 2048 + lo5 * 64;

  // ---- B fragment pointers (per nf sub-tile of 32 cols)
  const uint8_t* pB0 = Wt + ((size_t)(bn * 4 + 0) << 15) + lane * 16;
  const uint8_t* pB1 = pB0 + 32768;
  const uint8_t* pB2 = pB0 + 65536;
  const uint8_t* pB3 = pB0 + 98304;

  float4 rs0, rs1, rs2, rs3;                    // A staging regs (1 set, WAR-safe)
  bf16x8 a0, a1, a2, a3, a4, a5, a6, a7;        // B set A  [kk*4+nf]
  bf16x8 b0, b1, b2, b3, b4, b5, b6, b7;        // B set B
  f32x16 acc0 = {}, acc1 = {}, acc2 = {}, acc3 = {};

#define SEP()  asm volatile("" ::: "memory")
#define VM(N)  asm volatile("s_waitcnt vmcnt(" #N ")" ::: "memory")

#define LOADA(OFF) do {                                                       \
    rs0 = *(const float4*)(pA + (OFF));                                       \
    rs1 = *(const float4*)(pA + (OFF) + 4);                                   \
    rs2 = *(const float4*)(pA + (OFF) + 8);                                   \
    rs3 = *(const float4*)(pA + (OFF) + 12);                                  \
    SEP();                                                                    \
  } while (0)

#define LOADB(B0,B1,B2,B3,B4,B5,B6,B7, OFF) do {                              \
    B0 = *(const bf16x8*)(pB0 + (OFF));                                       \
    B1 = *(const bf16x8*)(pB1 + (OFF));                                       \
    B2 = *(const bf16x8*)(pB2 + (OFF));                                       \
    B3 = *(const bf16x8*)(pB3 + (OFF));                                       \
    B4 = *(const bf16x8*)(pB0 + (OFF) + 1024);                                \
    B5 = *(const bf16x8*)(pB1 + (OFF) + 1024);                                \
    B6 = *(const bf16x8*)(pB2 + (OFF) + 1024);                                \
    B7 = *(const bf16x8*)(pB3 + (OFF) + 1024);                                \
    SEP();                                                                    \
  } while (0)

#define CVTA(BUF) do {                                                        \
    *(uint4*)(&Ab[BUF][awr]) =                                                \
        make_uint4(pk2(rs0.x, rs0.y), pk2(rs0.z, rs0.w),                      \
                   pk2(rs1.x, rs1.y), pk2(rs1.z, rs1.w));                     \
    *(uint4*)(&Ab[BUF][awr + 16]) =                                           \
        make_uint4(pk2(rs2.x, rs2.y), pk2(rs2.z, rs2.w),                      \
                   pk2(rs3.x, rs3.y), pk2(rs3.z, rs3.w));                     \
    SEP();                                                                    \
  } while (0)

#define MFMA8(BUF, B0,B1,B2,B3,B4,B5,B6,B7) do {                              \
    bf16x8 fa0 = *(const bf16x8*)(&Ab[BUF][ard + (hi1 << 4)]);                \
    acc0 = __builtin_amdgcn_mfma_f32_32x32x16_bf16(fa0, B0, acc0, 0, 0, 0);   \
    acc1 = __builtin_amdgcn_mfma_f32_32x32x16_bf16(fa0, B1, acc1, 0, 0, 0);   \
    acc2 = __builtin_amdgcn_mfma_f32_32x32x16_bf16(fa0, B2, acc2, 0, 0, 0);   \
    acc3 = __builtin_amdgcn_mfma_f32_32x32x16_bf16(fa0, B3, acc3, 0, 0, 0);   \
    bf16x8 fa1 = *(const bf16x8*)(&Ab[BUF][ard + 32 + (hi1 << 4)]);           \
    acc0 = __builtin_amdgcn_mfma_f32_32x32x16_bf16(fa1, B4, acc0, 0, 0, 0);   \
    acc1 = __builtin_amdgcn_mfma_f32_32x32x16_bf16(fa1, B5, acc1, 0, 0, 0);   \
    acc2 = __builtin_amdgcn_mfma_f32_32x32x16_bf16(fa1, B6, acc2, 0, 0, 0);   \
    acc3 = __builtin_amdgcn_mfma_f32_32x32x16_bf16(fa1, B7, acc3, 0, 0, 0);   \
  } while (0)

  // ---- prologue: establish invariant queue [B(0):8, A(1):4]
  LOADA(0);                                  // A(0)
  LOADB(a0,a1,a2,a3,a4,a5,a6,a7, 0);         // B(0)
  VM(8);                                     // A(0) landed
  CVTA(0);                                   // buf0 <- A(0)
  LOADA(32);                                 // A(1)

  // ---- main loop: steps 0..13, two per iter. No barriers anywhere.
#pragma unroll 1
  for (int it = 0; it < 7; ++it) {
    // even step t=2it: compute buf0 x setA; prep buf1, setB
    LOADB(b0,b1,b2,b3,b4,b5,b6,b7, 2048);    // B(t+1)
    VM(12);                                  // B(t) landed
    MFMA8(0, a0,a1,a2,a3,a4,a5,a6,a7);
    VM(8);                                   // A(t+1) landed
    CVTA(1);                                 // buf1 <- A(t+1)
    LOADA(64);                               // A(t+2) (reuses rs: WAR at issue)
    pB0 += 4096; pB1 += 4096; pB2 += 4096; pB3 += 4096;
    // odd step t+1: compute buf1 x setB; prep buf0, setA
    LOADB(a0,a1,a2,a3,a4,a5,a6,a7, 0);       // B(t+2) (base just advanced)
    VM(12);                                  // B(t+1) landed
    MFMA8(1, b0,b1,b2,b3,b4,b5,b6,b7);
    VM(8);                                   // A(t+2) landed
    CVTA(0);                                 // buf0 <- A(t+2)
    LOADA(96);                               // A(t+3)
    pA += 64;
  }

  // ---- tail: step 14 (no A(16)), step 15 (drain)
  LOADB(b0,b1,b2,b3,b4,b5,b6,b7, 2048);      // B(15)
  VM(12);                                    // B(14) landed
  MFMA8(0, a0,a1,a2,a3,a4,a5,a6,a7);         // step 14
  VM(8);                                     // A(15) landed
  CVTA(1);
  VM(0);                                     // B(15) landed
  MFMA8(1, b0,b1,b2,b3,b4,b5,b6,b7);         // step 15

  // ---- epilogue: bias + tanh + fp32 store
  const int gnb  = bn * 128 + lo5;
  const int rowb = bm * 128 + wv * 32;

#define EPI(ACC, NF) do {                                                     \
    const float bv = Bv[gnb + (NF) * 32];                                     \
    _Pragma("unroll")                                                         \
    for (int r = 0; r < 16; ++r) {                                            \
      const int rl = (r & 3) + ((r >> 2) << 3) + (hi1 << 2);                  \
      Y[(size_t)(rowb + rl) * NTOT + gnb + (NF) * 32] =                       \
          fast_tanh((ACC)[r] + bv);                                           \
    }                                                                         \
  } while (0)

  EPI(acc0, 0);
  EPI(acc1, 1);
  EPI(acc2, 2);
  EPI(acc3, 3);
}

// ---------------- fallback: R1 kernel (146us), used if ws too small ----------
struct Regs {
  float4 a0,a1,a2,a3,a4,a5,a6,a7;
  float4 u0,u1,u2,u3;
  float4 v0,v1,v2,v3;
};

typedef uint32_t u32x4f __attribute__((ext_vector_type(4)));

__global__ __launch_bounds__(256, 2)
void hotdd_fallback(const float* __restrict__ X, const float* __restrict__ W,
                    const float* __restrict__ Bv, float* __restrict__ Y) {
  __shared__ char Ab[128 * 64 * 2];
  __shared__ char Bb[128 * 64 * 2];
  const int d  = blockIdx.x;
  const int bm = ((d >> 5) << 3) | (d & 7);
  const int bn = (d >> 3) & 3;
  const int tid  = threadIdx.x;
  const int lane = tid & 63;
  const int wv   = tid >> 6;
  const int wr   = (wv >> 1) * 64;
  const int wc   = (wv & 1) * 64;
  const int lo5  = lane & 31;
  const int hi1  = lane >> 5;
  const int rs   = lo5 & 7;
  const int am   = tid >> 1;
  const int ah   = tid & 1;
  const int amz  = am & 7;
  const int abase = am * 128;
  const float* Ag = X + (size_t)(bm * 128 + am) * KTOT + ah * 32;
  const int kp = lo5;
  const int ng = wv * 32 + hi1 * 16;
  const float* Bg = W + (size_t)(2 * kp) * NTOT + bn * 128 + ng;

#define LOADR(R, K0) do {                                                     \
    const float* ap_ = Ag + (K0);                                             \
    R.a0 = *(const float4*)(ap_ +  0); R.a1 = *(const float4*)(ap_ +  4);     \
    R.a2 = *(const float4*)(ap_ +  8); R.a3 = *(const float4*)(ap_ + 12);     \
    R.a4 = *(const float4*)(ap_ + 16); R.a5 = *(const float4*)(ap_ + 20);     \
    R.a6 = *(const float4*)(ap_ + 24); R.a7 = *(const float4*)(ap_ + 28);     \
    const float* bp_ = Bg + (size_t)(K0) * NTOT;                              \
    R.u0 = *(const float4*)(bp_ +  0); R.u1 = *(const float4*)(bp_ +  4);     \
    R.u2 = *(const float4*)(bp_ +  8); R.u3 = *(const float4*)(bp_ + 12);     \
    R.v0 = *(const float4*)(bp_ + NTOT +  0); R.v1 = *(const float4*)(bp_ + NTOT +  4); \
    R.v2 = *(const float4*)(bp_ + NTOT +  8); R.v3 = *(const float4*)(bp_ + NTOT + 12); \
  } while (0)

#define ASTF(R, J, P, Q)                                                      \
    *(uint4*)(Ab + abase + (((((ah << 2) + (J)) ^ amz)) << 4)) =              \
      make_uint4(pk2(R.P.x, R.P.y), pk2(R.P.z, R.P.w),                        \
                 pk2(R.Q.x, R.Q.y), pk2(R.Q.z, R.Q.w));
#define BSTF(R, I, UV, C)                                                     \
    *(uint32_t*)(Bb + (ng + (I)) * 128 + ((kp << 2) ^ (((I) & 7) << 4))) =    \
      pk2(R.u##UV.C, R.v##UV.C);

#define STORERF(R) do {                                                       \
    ASTF(R, 0, a0, a1) ASTF(R, 1, a2, a3) ASTF(R, 2, a4, a5) ASTF(R, 3, a6, a7)\
    BSTF(R, 0, 0, x) BSTF(R, 1, 0, y) BSTF(R, 2, 0, z) BSTF(R, 3, 0, w)       \
    BSTF(R, 4, 1, x) BSTF(R, 5, 1, y) BSTF(R, 6, 1, z) BSTF(R, 7, 1, w)       \
    BSTF(R, 8, 2, x) BSTF(R, 9, 2, y) BSTF(R,10, 2, z) BSTF(R,11, 2, w)       \
    BSTF(R,12, 3, x) BSTF(R,13, 3, y) BSTF(R,14, 3, z) BSTF(R,15, 3, w)       \
  } while (0)

  f32x16 acc00 = {}, acc01 = {}, acc10 = {}, acc11 = {};
  const char* Ard0 = Ab + (wr + lo5) * 128;
  const char* Ard1 = Ard0 + 32 * 128;
  const char* Brd0 = Bb + (wc + lo5) * 128;
  const char* Brd1 = Brd0 + 32 * 128;

#define MFMA_PHASE_F() do {                                                   \
    _Pragma("unroll")                                                         \
    for (int kk = 0; kk < 4; ++kk) {                                          \
      const int sb = ((((kk << 1) | hi1) ^ rs) << 4);                         \
      bf16x8 fa0 = *(const bf16x8*)(Ard0 + sb);                               \
      bf16x8 fa1 = *(const bf16x8*)(Ard1 + sb);                               \
      bf16x8 fb0 = *(const bf16x8*)(Brd0 + sb);                               \
      bf16x8 fb1 = *(const bf16x8*)(Brd1 + sb);                               \
      acc00 = __builtin_amdgcn_mfma_f32_32x32x16_bf16(fa0, fb0, acc00, 0,0,0);\
      acc01 = __builtin_amdgcn_mfma_f32_32x32x16_bf16(fa0, fb1, acc01, 0,0,0);\
      acc10 = __builtin_amdgcn_mfma_f32_32x32x16_bf16(fa1, fb0, acc10, 0,0,0);\
      acc11 = __builtin_amdgcn_mfma_f32_32x32x16_bf16(fa1, fb1, acc11, 0,0,0);\
    }                                                                         \
  } while (0)

  Regs r0, r1;
  LOADR(r0, 0);
#pragma unroll 1
  for (int s = 0; s < 8; s += 2) {
    STORERF(r0);
    __syncthreads();
    LOADR(r1, (s + 1) * 64);
    MFMA_PHASE_F();
    __syncthreads();
    STORERF(r1);
    __syncthreads();
    if (s + 2 < 8) LOADR(r0, (s + 2) * 64);
    MFMA_PHASE_F();
    __syncthreads();
  }

  const int gn0 = bn * 128 + wc + lo5;
  const int gn1 = gn0 + 32;
  const float bv0 = Bv[gn0];
  const float bv1 = Bv[gn1];

#define EPIF(ACC, MI, GN, BVAL) do {                                          \
    _Pragma("unroll")                                                         \
    for (int r = 0; r < 16; ++r) {                                            \
      const int mloc = wr + (MI) * 32 + (hi1 << 2) + ((r >> 2) << 3) + (r & 3);\
      Y[(size_t)(bm * 128 + mloc) * NTOT + (GN)] = fast_tanh((ACC)[r] + (BVAL));\
    }                                                                         \
  } while (0)

  EPIF(acc00, 0, gn0, bv0);
  EPIF(acc01, 0, gn1, bv1);
  EPIF(acc10, 1, gn0, bv0);
  EPIF(acc11, 1, gn1, bv1);
}

extern "C" void kernel_launch(void* const* d_in, const int* in_sizes, int n_in,
                              void* d_out, int out_size, void* d_ws, size_t ws_size,
                              hipStream_t stream) {
  (void)in_sizes; (void)n_in; (void)out_size;
  const float* X = (const float*)d_in[0];
  const float* W = (const float*)d_in[1];
  const float* b = (const float*)d_in[2];
  float* Y = (float*)d_out;
  if (ws_size >= WS_NEEDED) {
    uint8_t* Wt = (uint8_t*)d_ws;
    hipLaunchKernelGGL(cvtW_kernel, dim3(128),  dim3(256), 0, stream, W, Wt);
    hipLaunchKernelGGL(hotdd_fused, dim3(2048), dim3(256), 0, stream, X, Wt, b, Y);
  } else {
    hipLaunchKernelGGL(hotdd_fallback, dim3(2048), dim3(256), 0, stream, X, W, b, Y);
  }
}